// Round 2
// baseline (194.018 us; speedup 1.0000x reference)
//
#include <hip/hip_runtime.h>

#define SK 8192
#define SQ 8192
#define DD 128
#define ZSPLIT 8
#define QSPLIT 8

typedef __attribute__((ext_vector_type(8))) short short8;
typedef __attribute__((ext_vector_type(4))) float f32x4;
typedef unsigned short ushort_t;

// round-to-nearest-even f32 -> bf16
__device__ __forceinline__ unsigned short f2bf(float x){
  unsigned int u = __float_as_uint(x);
  u += 0x7FFFu + ((u >> 16) & 1u);
  return (unsigned short)(u >> 16);
}

// ---------------------------------------------------------------------------
// prep_kq: cast K (pre-scaled by log2(e)/sqrt(128)) and Q to bf16, stored as
// pre-swizzled 64-row tile images (row stride 256B, 16B-slot XOR swizzle):
// element (row r in tile, d): byte = r*256 + (((d>>3)*16) ^ ((r&7)<<4)) + (d&7)*2
// ---------------------------------------------------------------------------
__global__ __launch_bounds__(256) void prep_kq(const float* __restrict__ Kp,
                                               const float* __restrict__ Qp,
                                               ushort_t* __restrict__ kws,
                                               ushort_t* __restrict__ qws){
  int g = blockIdx.x*256 + threadIdx.x;
  int arr = g >> 17;
  int s   = g & 131071;
  int row = s >> 4;
  int c16 = s & 15;
  const float* src = (arr ? Qp : Kp) + row*DD + c16*8;
  const float scale = arr ? 1.0f : 0.12751743f;   // log2(e)/sqrt(128)
  float4 f0 = ((const float4*)src)[0];
  float4 f1 = ((const float4*)src)[1];
  unsigned int wv[4];
  wv[0] = (unsigned)f2bf(f0.x*scale) | ((unsigned)f2bf(f0.y*scale) << 16);
  wv[1] = (unsigned)f2bf(f0.z*scale) | ((unsigned)f2bf(f0.w*scale) << 16);
  wv[2] = (unsigned)f2bf(f1.x*scale) | ((unsigned)f2bf(f1.y*scale) << 16);
  wv[3] = (unsigned)f2bf(f1.z*scale) | ((unsigned)f2bf(f1.w*scale) << 16);
  ushort_t* base = arr ? qws : kws;
  int tile = row >> 6, r = row & 63;
  char* dst = (char*)(base + (size_t)tile*8192) + r*256 + ((c16*16) ^ ((r&7)<<4));
  ((uint4*)dst)[0] = make_uint4(wv[0],wv[1],wv[2],wv[3]);
}

// ---------------------------------------------------------------------------
// prep_v: V -> V^T tile images: per 64-q tile, [128 dv][64 q] bf16,
// row stride 128B, 16B-slot XOR swizzle with f(dv)=dv&7:
// element (dv, q): byte = dv*128 + ((((q&63)>>3)*16) ^ ((dv&7)<<4)) + (q&7)*2
// ---------------------------------------------------------------------------
__global__ __launch_bounds__(256) void prep_v(const float* __restrict__ Vp,
                                              ushort_t* __restrict__ vtws){
  __shared__ ushort_t vl[64][132];
  int tile = blockIdx.x;    // 0..127
  int t = threadIdx.x;
  int q = t >> 2, dvb = (t & 3)*32;
  const float* src = Vp + (size_t)(tile*64 + q)*DD + dvb;
  #pragma unroll
  for (int j=0;j<8;j++){
    float4 f = ((const float4*)src)[j];
    vl[q][dvb + j*4 + 0] = f2bf(f.x);
    vl[q][dvb + j*4 + 1] = f2bf(f.y);
    vl[q][dvb + j*4 + 2] = f2bf(f.z);
    vl[q][dvb + j*4 + 3] = f2bf(f.w);
  }
  __syncthreads();
  char* obase = (char*)(vtws + (size_t)tile*8192);
  #pragma unroll
  for (int s2=0;s2<4;s2++){
    int sid = t*4 + s2;
    int dv = sid >> 3, qs = sid & 7;
    unsigned int wv[4];
    #pragma unroll
    for (int p=0;p<4;p++){
      unsigned lo = vl[qs*8 + p*2 + 0][dv];
      unsigned hi = vl[qs*8 + p*2 + 1][dv];
      wv[p] = lo | (hi << 16);
    }
    char* dst = obase + dv*128 + ((qs*16) ^ ((dv&7)<<4));
    ((uint4*)dst)[0] = make_uint4(wv[0],wv[1],wv[2],wv[3]);
  }
}

// ---------------------------------------------------------------------------
// kz: per-column stats with K-tile register prefetch.
// ---------------------------------------------------------------------------
__global__ __launch_bounds__(256) void kz(const ushort_t* __restrict__ kws,
                                          const ushort_t* __restrict__ qws,
                                          float* __restrict__ zpart){
  __shared__ ushort_t Qs[8192];
  __shared__ ushort_t Ks[8192];
  int wg = blockIdx.x;            // 1024
  int qs   = wg >> 3;             // 0..127
  int kspl = wg & 7;
  int t = threadIdx.x, lane = t & 63, w = t >> 6;
  int r15 = lane & 15, g4 = lane >> 4;
  uint4 pk[4];
  { const uint4* srcq = (const uint4*)(qws + (size_t)qs*8192);
    uint4* d = (uint4*)Qs;
    #pragma unroll
    for (int i=0;i<4;i++) d[t+i*256] = srcq[t+i*256];
    const uint4* sk = (const uint4*)(kws + (size_t)(kspl*16)*8192);
    #pragma unroll
    for (int i=0;i<4;i++) pk[i] = sk[t+i*256];
    uint4* dk = (uint4*)Ks;
    #pragma unroll
    for (int i=0;i<4;i++) dk[t+i*256] = pk[i]; }
  __syncthreads();
  float zacc = 0.f;
  for (int it=0; it<16; ++it){
    if (it+1 < 16){
      const uint4* sk = (const uint4*)(kws + (size_t)(kspl*16+it+1)*8192);
      #pragma unroll
      for (int i=0;i<4;i++) pk[i] = sk[t+i*256];
    }
    #pragma unroll
    for (int mf=0; mf<4; ++mf){
      f32x4 s = {0.f,0.f,0.f,0.f};
      #pragma unroll
      for (int kk=0; kk<4; ++kk){
        int arow = mf*16 + r15;
        short8 a = *(const short8*)((const char*)Ks + arow*256 + ((kk*64 + g4*16) ^ ((arow&7)<<4)));
        int brow = w*16 + r15;
        short8 b = *(const short8*)((const char*)Qs + brow*256 + ((kk*64 + g4*16) ^ ((brow&7)<<4)));
        s = __builtin_amdgcn_mfma_f32_16x16x32_bf16(a, b, s, 0, 0, 0);
      }
      zacc += __builtin_exp2f(s[0]) + __builtin_exp2f(s[1])
            + __builtin_exp2f(s[2]) + __builtin_exp2f(s[3]);
    }
    __syncthreads();
    if (it+1 < 16){
      uint4* dk = (uint4*)Ks;
      #pragma unroll
      for (int i=0;i<4;i++) dk[t+i*256] = pk[i];
    }
    __syncthreads();
  }
  zacc += __shfl_xor(zacc, 16);
  zacc += __shfl_xor(zacc, 32);
  if (lane < 16)
    zpart[(size_t)kspl*SQ + qs*64 + w*16 + lane] = zacc;
}

// c_q = log2( sum of partials )
__global__ __launch_bounds__(256) void kc(const float* __restrict__ zpart,
                                          float* __restrict__ carr){
  int q = blockIdx.x*256 + threadIdx.x;
  float z = 0.f;
  #pragma unroll
  for (int s=0;s<ZSPLIT;s++) z += zpart[(size_t)s*SQ + q];
  carr[q] = __builtin_log2f(z);
}

// ---------------------------------------------------------------------------
// ko: main fused pass. Grid = 64 k-tiles x 8 q-splits = 512 WGs (2 blocks/CU).
// Q/V tiles register-prefetched one iteration ahead.
// Ps swizzle f(row) = (row>>1)&7 so the 4 write-row groups (g4*4+j) hit
// 4 distinct 16B slots -> conflict-free writes; reads 2-way (free).
// ---------------------------------------------------------------------------
__global__ __launch_bounds__(512) void ko(const ushort_t* __restrict__ kws,
                                          const ushort_t* __restrict__ qws,
                                          const ushort_t* __restrict__ vtws,
                                          const float* __restrict__ carr,
                                          float* __restrict__ out){
  __shared__ ushort_t Ks[16384];  // 32KB
  __shared__ ushort_t Qs[8192];   // 16KB
  __shared__ ushort_t Vs[8192];   // 16KB
  __shared__ ushort_t Ps[8192];   // 16KB
  int wg = blockIdx.x;            // 512
  int ktile = wg >> 3;            // 0..63
  int qsp   = wg & 7;             // 0..7  (same qsp -> same XCD under %8 round-robin)
  int t = threadIdx.x, lane = t & 63, w = t >> 6;
  int wm = w >> 2, wn = w & 3;
  int r15 = lane & 15, g4 = lane >> 4;
  uint4 pq[2], pv[2];
  { const uint4* src = (const uint4*)(kws + (size_t)ktile*16384);
    uint4* d = (uint4*)Ks;
    #pragma unroll
    for (int i=0;i<4;i++) d[t+i*512] = src[t+i*512];
    const uint4* sq = (const uint4*)(qws + (size_t)(qsp*16)*8192);
    const uint4* sv = (const uint4*)(vtws + (size_t)(qsp*16)*8192);
    #pragma unroll
    for (int i=0;i<2;i++){ pq[i]=sq[t+i*512]; pv[i]=sv[t+i*512]; }
    uint4* dq = (uint4*)Qs; uint4* dvp = (uint4*)Vs;
    #pragma unroll
    for (int i=0;i<2;i++){ dq[t+i*512]=pq[i]; dvp[t+i*512]=pv[i]; } }
  __syncthreads();
  f32x4 zero = {0.f,0.f,0.f,0.f};
  f32x4 acc[4][2];
  #pragma unroll
  for (int i=0;i<4;i++){ acc[i][0]=zero; acc[i][1]=zero; }

  for (int it=0; it<16; ++it){
    int qt = qsp*16 + it;
    if (it+1 < 16){
      const uint4* sq = (const uint4*)(qws + (size_t)(qt+1)*8192);
      const uint4* sv = (const uint4*)(vtws + (size_t)(qt+1)*8192);
      #pragma unroll
      for (int i=0;i<2;i++){ pq[i]=sq[t+i*512]; pv[i]=sv[t+i*512]; }
    }
    float c_lane = carr[qt*64 + wn*16 + r15];
    // ---- G1: scores + exp2 -> Ps ----
    #pragma unroll
    for (int mf=0; mf<4; ++mf){
      f32x4 s = {0.f,0.f,0.f,0.f};
      #pragma unroll
      for (int kk=0; kk<4; ++kk){
        int arow = wm*64 + mf*16 + r15;
        const char* kbase = (const char*)Ks + (arow>>6)*16384;
        int ar = arow & 63;
        short8 a = *(const short8*)(kbase + ar*256 + ((kk*64 + g4*16) ^ ((ar&7)<<4)));
        int brow = wn*16 + r15;
        short8 b = *(const short8*)((const char*)Qs + brow*256 + ((kk*64 + g4*16) ^ ((brow&7)<<4)));
        s = __builtin_amdgcn_mfma_f32_16x16x32_bf16(a, b, s, 0, 0, 0);
      }
      #pragma unroll
      for (int j=0;j<4;j++){
        float p = __builtin_exp2f(s[j] - c_lane);
        int prow = wm*64 + mf*16 + g4*4 + j;      // C layout: row=(lane>>4)*4+j
        int pcolb = (wn*16 + r15)*2;              // col = lane&15
        *(ushort_t*)((char*)Ps + prow*128 + ((pcolb & ~15) ^ (((prow>>1)&7)<<4)) + (pcolb & 15)) = f2bf(p);
      }
    }
    __syncthreads();
    // ---- G2: O += P . V ----
    #pragma unroll
    for (int kk=0; kk<2; ++kk){
      int dv0 = wn*32 + r15;
      short8 b0 = *(const short8*)((const char*)Vs + dv0*128 + (((kk*4+g4)*16) ^ ((dv0&7)<<4)));
      int dv1 = wn*32 + 16 + r15;
      short8 b1 = *(const short8*)((const char*)Vs + dv1*128 + (((kk*4+g4)*16) ^ ((dv1&7)<<4)));
      #pragma unroll
      for (int mf=0; mf<4; ++mf){
        int prow = wm*64 + mf*16 + r15;
        short8 a = *(const short8*)((const char*)Ps + prow*128 + (((kk*4+g4)*16) ^ (((prow>>1)&7)<<4)));
        acc[mf][0] = __builtin_amdgcn_mfma_f32_16x16x32_bf16(a, b0, acc[mf][0], 0, 0, 0);
        acc[mf][1] = __builtin_amdgcn_mfma_f32_16x16x32_bf16(a, b1, acc[mf][1], 0, 0, 0);
      }
    }
    __syncthreads();
    if (it+1 < 16){
      uint4* dq = (uint4*)Qs; uint4* dvp = (uint4*)Vs;
      #pragma unroll
      for (int i=0;i<2;i++){ dq[t+i*512]=pq[i]; dvp[t+i*512]=pv[i]; }
    }
    __syncthreads();
  }
  // ---- epilogue: accumulate across the 8 q-split WGs ----
  #pragma unroll
  for (int mf=0; mf<4; ++mf)
    #pragma unroll
    for (int nf=0; nf<2; ++nf)
      #pragma unroll
      for (int j=0;j<4;j++){
        int k  = ktile*128 + wm*64 + mf*16 + g4*4 + j;
        int dv = wn*32 + nf*16 + r15;
        atomicAdd(out + (size_t)k*DD + dv, acc[mf][nf][j]);
      }
}

extern "C" void kernel_launch(void* const* d_in, const int* in_sizes, int n_in,
                              void* d_out, int out_size, void* d_ws, size_t ws_size,
                              hipStream_t stream) {
  const float* Kp = (const float*)d_in[0];
  const float* Qp = (const float*)d_in[1];
  const float* Vp = (const float*)d_in[2];
  float* out = (float*)d_out;
  char* ws = (char*)d_ws;
  ushort_t* kws  = (ushort_t*)ws;
  ushort_t* qws  = (ushort_t*)(ws + ((size_t)2<<20));
  ushort_t* vtws = (ushort_t*)(ws + ((size_t)4<<20));
  float* zpart   = (float*)(ws + ((size_t)6<<20));
  float* carr    = (float*)(ws + ((size_t)6<<20) + ((size_t)256<<10));

  hipMemsetAsync(d_out, 0, (size_t)SK*DD*sizeof(float), stream);
  prep_kq<<<dim3(1024), dim3(256), 0, stream>>>(Kp, Qp, kws, qws);
  prep_v <<<dim3(128),  dim3(256), 0, stream>>>(Vp, vtws);
  kz     <<<dim3(1024), dim3(256), 0, stream>>>(kws, qws, zpart);
  kc     <<<dim3(SQ/256), dim3(256), 0, stream>>>(zpart, carr);
  ko     <<<dim3(512),  dim3(512), 0, stream>>>(kws, qws, vtws, carr, out);
}

// Round 4
// 119.573 us; speedup vs baseline: 1.6226x; 1.6226x over previous
//
#include <hip/hip_runtime.h>

#define SK 8192
#define SQ 8192
#define DD 128
#define ZSPLIT 8
#define QSPLIT 8

typedef __attribute__((ext_vector_type(8))) short short8;
typedef __attribute__((ext_vector_type(4))) float f32x4;
typedef __attribute__((ext_vector_type(4))) unsigned uint4v;
typedef unsigned short ushort_t;

// round-to-nearest-even f32 -> bf16
__device__ __forceinline__ unsigned short f2bf(float x){
  unsigned int u = __float_as_uint(x);
  u += 0x7FFFu + ((u >> 16) & 1u);
  return (unsigned short)(u >> 16);
}

// async global->LDS DMA, 16B/lane. LDS dest = uniform base + lane*16,
// global src = per-lane address.
__device__ __forceinline__ void gld16(const void* g, void* l){
  __builtin_amdgcn_global_load_lds(
      (const __attribute__((address_space(1))) unsigned int*)g,
      (__attribute__((address_space(3))) unsigned int*)l, 16, 0, 0);
}

// ---------------------------------------------------------------------------
// prep_kq: cast K (pre-scaled by log2(e)/sqrt(128)) and Q to bf16, stored as
// pre-swizzled 64-row tile images (row stride 256B, 16B-slot XOR swizzle):
// element (row r, d): byte = r*256 + (((d>>3)*16) ^ ((r&7)<<4)) + (d&7)*2
// ---------------------------------------------------------------------------
__global__ __launch_bounds__(256) void prep_kq(const float* __restrict__ Kp,
                                               const float* __restrict__ Qp,
                                               ushort_t* __restrict__ kws,
                                               ushort_t* __restrict__ qws){
  int g = blockIdx.x*256 + threadIdx.x;
  int arr = g >> 17;
  int s   = g & 131071;
  int row = s >> 4;
  int c16 = s & 15;
  const float* src = (arr ? Qp : Kp) + row*DD + c16*8;
  const float scale = arr ? 1.0f : 0.12751743f;   // log2(e)/sqrt(128)
  float4 f0 = ((const float4*)src)[0];
  float4 f1 = ((const float4*)src)[1];
  unsigned int wv[4];
  wv[0] = (unsigned)f2bf(f0.x*scale) | ((unsigned)f2bf(f0.y*scale) << 16);
  wv[1] = (unsigned)f2bf(f0.z*scale) | ((unsigned)f2bf(f0.w*scale) << 16);
  wv[2] = (unsigned)f2bf(f1.x*scale) | ((unsigned)f2bf(f1.y*scale) << 16);
  wv[3] = (unsigned)f2bf(f1.z*scale) | ((unsigned)f2bf(f1.w*scale) << 16);
  ushort_t* base = arr ? qws : kws;
  int tile = row >> 6, r = row & 63;
  char* dst = (char*)(base + (size_t)tile*8192) + r*256 + ((c16*16) ^ ((r&7)<<4));
  ((uint4*)dst)[0] = make_uint4(wv[0],wv[1],wv[2],wv[3]);
}

// ---------------------------------------------------------------------------
// prep_v: V -> V^T tile images: per 64-q tile, [128 dv][64 q] bf16,
// row stride 128B: byte = dv*128 + (((q>>3)*16) ^ ((dv&7)<<4)) + (q&7)*2
// ---------------------------------------------------------------------------
__global__ __launch_bounds__(256) void prep_v(const float* __restrict__ Vp,
                                              ushort_t* __restrict__ vtws){
  __shared__ ushort_t vl[64][132];
  int tile = blockIdx.x;    // 0..127
  int t = threadIdx.x;
  int q = t >> 2, dvb = (t & 3)*32;
  const float* src = Vp + (size_t)(tile*64 + q)*DD + dvb;
  #pragma unroll
  for (int j=0;j<8;j++){
    float4 f = ((const float4*)src)[j];
    vl[q][dvb + j*4 + 0] = f2bf(f.x);
    vl[q][dvb + j*4 + 1] = f2bf(f.y);
    vl[q][dvb + j*4 + 2] = f2bf(f.z);
    vl[q][dvb + j*4 + 3] = f2bf(f.w);
  }
  __syncthreads();
  char* obase = (char*)(vtws + (size_t)tile*8192);
  #pragma unroll
  for (int s2=0;s2<4;s2++){
    int sid = t*4 + s2;
    int dv = sid >> 3, qs = sid & 7;
    unsigned int wv[4];
    #pragma unroll
    for (int p=0;p<4;p++){
      unsigned lo = vl[qs*8 + p*2 + 0][dv];
      unsigned hi = vl[qs*8 + p*2 + 1][dv];
      wv[p] = lo | (hi << 16);
    }
    char* dst = obase + dv*128 + ((qs*16) ^ ((dv&7)<<4));
    ((uint4*)dst)[0] = make_uint4(wv[0],wv[1],wv[2],wv[3]);
  }
}

// ---------------------------------------------------------------------------
// kz: per-column stats. Q-frags hoisted to regs; K double-buffered via
// global_load_lds; 1 barrier per iteration. LDS 32KB -> 5 blocks/CU.
// ---------------------------------------------------------------------------
__global__ __launch_bounds__(256, 5) void kz(const ushort_t* __restrict__ kws,
                                             const ushort_t* __restrict__ qws,
                                             float* __restrict__ zpart){
  __shared__ __align__(16) char smem[32768];   // buf0 16KB | buf1 16KB
  int wg = blockIdx.x;            // 1024
  int qs   = wg >> 3;             // 0..127 (64-q stripe)
  int kspl = wg & 7;
  int t = threadIdx.x, lane = t & 63, w = t >> 6;
  int r15 = lane & 15, g4 = lane >> 4;

  // stage Q stripe image (16KB) into buf0
  { const char* qg = (const char*)qws + (size_t)qs*16384;
    #pragma unroll
    for (int i=0;i<4;i++)
      gld16(qg + (w*4+i)*1024 + lane*16, smem + (w*4+i)*1024);
  }
  __syncthreads();
  // hoist Q B-frags (wave's 16 q-cols) into registers
  short8 qf[4];
  { int qrow = w*16 + r15;
    const char* qb = smem + qrow*256;
    int sw = (qrow & 7) << 4;
    #pragma unroll
    for (int kk=0;kk<4;kk++)
      qf[kk] = *(const short8*)(qb + ((kk*64 + g4*16) ^ sw));
  }
  __syncthreads();
  // stage K tile 0 into buf0 (safe: all waves have read Q)
  { const char* kg = (const char*)kws + (size_t)(kspl*16)*16384;
    #pragma unroll
    for (int i=0;i<4;i++)
      gld16(kg + (w*4+i)*1024 + lane*16, smem + (w*4+i)*1024);
  }
  __syncthreads();

  float zacc = 0.f;
  for (int it=0; it<16; ++it){
    if (it+1 < 16){
      const char* kg = (const char*)kws + (size_t)(kspl*16+it+1)*16384;
      char* dst = smem + ((it+1)&1)*16384;
      #pragma unroll
      for (int i=0;i<4;i++)
        gld16(kg + (w*4+i)*1024 + lane*16, dst + (w*4+i)*1024);
    }
    const char* Kb = smem + (it&1)*16384;
    #pragma unroll
    for (int mf=0; mf<4; ++mf){
      f32x4 s = {0.f,0.f,0.f,0.f};
      #pragma unroll
      for (int kk=0; kk<4; ++kk){
        int arow = mf*16 + r15;
        short8 ak = *(const short8*)(Kb + arow*256 + ((kk*64 + g4*16) ^ ((arow&7)<<4)));
        s = __builtin_amdgcn_mfma_f32_16x16x32_bf16(ak, qf[kk], s, 0, 0, 0);
      }
      zacc += __builtin_exp2f(s[0]) + __builtin_exp2f(s[1])
            + __builtin_exp2f(s[2]) + __builtin_exp2f(s[3]);
    }
    __syncthreads();
  }
  zacc += __shfl_xor(zacc, 16);
  zacc += __shfl_xor(zacc, 32);
  if (lane < 16)
    zpart[(size_t)kspl*SQ + qs*64 + w*16 + lane] = zacc;
}

// c_q = log2( sum of partials )
__global__ __launch_bounds__(256) void kc(const float* __restrict__ zpart,
                                          float* __restrict__ carr){
  int q = blockIdx.x*256 + threadIdx.x;
  float z = 0.f;
  #pragma unroll
  for (int s=0;s<ZSPLIT;s++) z += zpart[(size_t)s*SQ + q];
  carr[q] = __builtin_log2f(z);
}

// ---------------------------------------------------------------------------
// ko: fused main pass, in-register P (no Ps LDS round-trip).
// Grid = 64 k-tiles x 8 q-splits = 512 WGs x 512 thr (2 blocks/CU).
// Wave w owns k-rows [w*16, w*16+16). Per 64-q tile:
//   S^T = Q.K (swapped MFMA: A=Q rows=q, B=K cols=k -> k lands in lane&15),
//   acc init = -c_q (c broadcast from LDS), exp2 in-register,
//   cvt_pk -> bf16 words, UNCONDITIONAL shfl_xor(32/16) + value-selects
//   redistribute -> PV A-frags (shfls hoisted out of ternaries: convergent
//   ops must run with full exec, not inside a divergent branch),
//   O[16k x 128dv] += P.V.  1 barrier/iter; Q/V double-buffered gld_lds.
// ---------------------------------------------------------------------------
__global__ __launch_bounds__(512, 4) void ko(const ushort_t* __restrict__ kws,
                                             const ushort_t* __restrict__ qws,
                                             const ushort_t* __restrict__ vtws,
                                             const float* __restrict__ carr,
                                             float* __restrict__ out){
  // buf0 [0,32K): Q 16K | V 16K ; buf1 [32K,64K) ; cs [64K, 68K)
  __shared__ __align__(16) char smem[69632];
  int wg = blockIdx.x;            // 512
  int ktile = wg >> 3;            // 0..63
  int qsp   = wg & 7;
  int t = threadIdx.x, lane = t & 63, w = t >> 6;
  int r15 = lane & 15, g4 = lane >> 4;
  bool hi16 = (lane & 16) != 0, hi32 = (lane & 32) != 0;

  // ---- prologue: stage K (32KB) into buf region + c (4KB) ----
  { const char* kg = (const char*)kws + (size_t)ktile*32768;
    #pragma unroll
    for (int i=0;i<4;i++)
      gld16(kg + (w*4+i)*1024 + lane*16, smem + (w*4+i)*1024);
    if (w < 4){
      const char* cg = (const char*)(carr + (size_t)qsp*1024);
      gld16(cg + w*1024 + lane*16, smem + 65536 + w*1024);
    }
  }
  __syncthreads();
  // hoist K B-frags (wave's 16 k-rows) into registers
  short8 kf[4];
  { int r = w*16 + r15;
    const char* kb = smem + (r>>6)*16384 + (r&63)*256;
    int sw = (r & 7) << 4;
    #pragma unroll
    for (int kk=0;kk<4;kk++)
      kf[kk] = *(const short8*)(kb + ((kk*64 + g4*16) ^ sw));
  }
  __syncthreads();
  // stage Q0/V0 into buf0
  { int qt = qsp*16;
    const char* qg = (const char*)qws  + (size_t)qt*16384;
    const char* vg = (const char*)vtws + (size_t)qt*16384;
    #pragma unroll
    for (int i=0;i<2;i++){
      gld16(qg + (w*2+i)*1024 + lane*16, smem + (w*2+i)*1024);
      gld16(vg + (w*2+i)*1024 + lane*16, smem + 16384 + (w*2+i)*1024);
    }
  }
  __syncthreads();

  f32x4 zero = {0.f,0.f,0.f,0.f};
  f32x4 acc[8];
  #pragma unroll
  for (int i=0;i<8;i++) acc[i] = zero;

  for (int it=0; it<16; ++it){
    // prefetch next Q/V into other buffer (async DMA; drained by end barrier)
    if (it+1 < 16){
      int qt = qsp*16 + it + 1;
      const char* qg = (const char*)qws  + (size_t)qt*16384;
      const char* vg = (const char*)vtws + (size_t)qt*16384;
      char* dst = smem + ((it+1)&1)*32768;
      #pragma unroll
      for (int i=0;i<2;i++){
        gld16(qg + (w*2+i)*1024 + lane*16, dst + (w*2+i)*1024);
        gld16(vg + (w*2+i)*1024 + lane*16, dst + 16384 + (w*2+i)*1024);
      }
    }
    const char* Qb = smem + (it&1)*32768;
    const char* Vb = Qb + 16384;
    short8 afrag[2];
    // ---- G1: S^T blocks + exp2 + pack + redistribute ----
    #pragma unroll
    for (int qc=0; qc<2; ++qc){
      unsigned pw[4];
      #pragma unroll
      for (int blk=0; blk<2; ++blk){
        // acc init = -c for rows q = qc*32+blk*16+g4*4+j (broadcast read)
        f32x4 cv = *(const f32x4*)(smem + 65536 + (size_t)(it*64 + qc*32 + blk*16 + g4*4)*4);
        f32x4 s = { -cv[0], -cv[1], -cv[2], -cv[3] };
        #pragma unroll
        for (int kk=0; kk<4; ++kk){
          int qrow = qc*32 + blk*16 + r15;
          short8 aq = *(const short8*)(Qb + qrow*256 + ((kk*64 + g4*16) ^ ((qrow&7)<<4)));
          s = __builtin_amdgcn_mfma_f32_16x16x32_bf16(aq, kf[kk], s, 0, 0, 0);
        }
        float p0 = __builtin_exp2f(s[0]);
        float p1 = __builtin_exp2f(s[1]);
        float p2 = __builtin_exp2f(s[2]);
        float p3 = __builtin_exp2f(s[3]);
        unsigned w0, w1;
        asm("v_cvt_pk_bf16_f32 %0, %1, %2" : "=v"(w0) : "v"(p0), "v"(p1));
        asm("v_cvt_pk_bf16_f32 %0, %1, %2" : "=v"(w1) : "v"(p2), "v"(p3));
        pw[blk*2+0] = w0;   // q = 4g+0,4g+1   (+blk*16)
        pw[blk*2+1] = w1;   // q = 4g+2,4g+3
      }
      // redistribute: lane(g,r15) ends with q = 8g..8g+7 at k=r15.
      // ALL shfls unconditional (full exec); selection via v_cndmask only.
      unsigned A = pw[0], B = pw[1], C = pw[2], D = pw[3];
      unsigned Ax = __shfl_xor(A,32);
      unsigned Bx = __shfl_xor(B,32);
      unsigned Cx = __shfl_xor(C,32);
      unsigned Dx = __shfl_xor(D,32);
      unsigned A2 = hi32 ? Cx : A;
      unsigned C2 = hi32 ? C  : Ax;
      unsigned B2 = hi32 ? Dx : B;
      unsigned D2 = hi32 ? D  : Bx;
      unsigned A2x = __shfl_xor(A2,16);
      unsigned B2x = __shfl_xor(B2,16);
      unsigned C2x = __shfl_xor(C2,16);
      unsigned D2x = __shfl_xor(D2,16);
      unsigned A3 = hi16 ? C2x : A2;
      unsigned C3 = hi16 ? C2  : A2x;
      unsigned B3 = hi16 ? D2x : B2;
      unsigned D3 = hi16 ? D2  : B2x;
      uint4v fw = { A3, B3, C3, D3 };
      afrag[qc] = __builtin_bit_cast(short8, fw);
    }
    // ---- PV: O += P.V ----
    #pragma unroll
    for (int dvb=0; dvb<8; ++dvb){
      #pragma unroll
      for (int qc=0; qc<2; ++qc){
        int dv = dvb*16 + r15;
        short8 bv = *(const short8*)(Vb + dv*128 + (((qc*4 + g4)*16) ^ ((dv&7)<<4)));
        acc[dvb] = __builtin_amdgcn_mfma_f32_16x16x32_bf16(afrag[qc], bv, acc[dvb], 0, 0, 0);
      }
    }
    __syncthreads();
  }
  // ---- epilogue: accumulate across the 8 q-split WGs ----
  #pragma unroll
  for (int dvb=0; dvb<8; ++dvb)
    #pragma unroll
    for (int j=0;j<4;j++){
      int k  = ktile*128 + w*16 + g4*4 + j;
      int dv = dvb*16 + r15;
      atomicAdd(out + (size_t)k*DD + dv, acc[dvb][j]);
    }
}

extern "C" void kernel_launch(void* const* d_in, const int* in_sizes, int n_in,
                              void* d_out, int out_size, void* d_ws, size_t ws_size,
                              hipStream_t stream) {
  const float* Kp = (const float*)d_in[0];
  const float* Qp = (const float*)d_in[1];
  const float* Vp = (const float*)d_in[2];
  float* out = (float*)d_out;
  char* ws = (char*)d_ws;
  ushort_t* kws  = (ushort_t*)ws;
  ushort_t* qws  = (ushort_t*)(ws + ((size_t)2<<20));
  ushort_t* vtws = (ushort_t*)(ws + ((size_t)4<<20));
  float* zpart   = (float*)(ws + ((size_t)6<<20));
  float* carr    = (float*)(ws + ((size_t)6<<20) + ((size_t)256<<10));

  hipMemsetAsync(d_out, 0, (size_t)SK*DD*sizeof(float), stream);
  prep_kq<<<dim3(1024), dim3(256), 0, stream>>>(Kp, Qp, kws, qws);
  prep_v <<<dim3(128),  dim3(256), 0, stream>>>(Vp, vtws);
  kz     <<<dim3(1024), dim3(256), 0, stream>>>(kws, qws, zpart);
  kc     <<<dim3(SQ/256), dim3(256), 0, stream>>>(zpart, carr);
  ko     <<<dim3(512),  dim3(512), 0, stream>>>(kws, qws, vtws, carr, out);
}